// Round 1
// baseline (46.001 us; speedup 1.0000x reference)
//
#include <hip/hip_runtime.h>

// FrequencyAdaptiveNorm: per-timestep LayerNorm(F=256) + mask-weighted affine.
// x: (B=32, S=4096, F=256) f32; gamma,beta: (3,256) f32; weights: (3,) f32.
// out[b,t,f] = xhat[b,t,f]*Gsum(t,f) + Bsum(t,f), masked at sequence borders.

#define S_LEN 4096
#define F_LEN 256
#define EPSV 1e-5f

__global__ __launch_bounds__(256) void fan_ln_kernel(
    const float* __restrict__ x,
    const float* __restrict__ gamma,
    const float* __restrict__ beta,
    const float* __restrict__ weights,
    float* __restrict__ out,
    int n_rows)
{
    const int wave = threadIdx.x >> 6;      // 4 waves/block, 1 row/wave
    const int lane = threadIdx.x & 63;      // 64 lanes * float4 = 256 feats
    const int row = blockIdx.x * 4 + wave;
    if (row >= n_rows) return;

    const int t = row & (S_LEN - 1);        // timestep within sequence
    const size_t base = (size_t)row * F_LEN;

    // ---- softmax over the 3 aggregation logits (uniform scalars) ----
    float l0 = weights[0], l1 = weights[1], l2 = weights[2];
    float mx = fmaxf(l0, fmaxf(l1, l2));
    float e0 = expf(l0 - mx), e1 = expf(l1 - mx), e2 = expf(l2 - mx);
    float inv = 1.0f / (e0 + e1 + e2);
    float w0 = e0 * inv, w1 = e1 * inv, w2 = e2 * inv;

    // ---- border masks (valid unfold range per window size) ----
    // ws=5 : c=2,  L=4092 -> [2, 4094)
    // ws=10: c=5,  L=4087 -> [5, 4092)
    // ws=20: c=10, L=4077 -> [10, 4087)
    const float m0 = (t >= 2  && t < 4094) ? w0 : 0.0f;
    const float m1 = (t >= 5  && t < 4092) ? w1 : 0.0f;
    const float m2 = (t >= 10 && t < 4087) ? w2 : 0.0f;

    // ---- load this lane's 4 features ----
    const float4 xv = reinterpret_cast<const float4*>(x + base)[lane];

    float s  = xv.x + xv.y + xv.z + xv.w;
    float sq = xv.x*xv.x + xv.y*xv.y + xv.z*xv.z + xv.w*xv.w;

    // ---- wave-wide butterfly reduction (64 lanes) ----
    #pragma unroll
    for (int off = 32; off >= 1; off >>= 1) {
        s  += __shfl_xor(s,  off);
        sq += __shfl_xor(sq, off);
    }

    const float mean = s * (1.0f / F_LEN);
    const float var  = sq * (1.0f / F_LEN) - mean * mean;
    const float rstd = rsqrtf(var + EPSV);

    // ---- per-feature fused affine: G = sum m_i*gamma_i, Bv = sum m_i*beta_i ----
    const float4 g0 = reinterpret_cast<const float4*>(gamma + 0 * F_LEN)[lane];
    const float4 g1 = reinterpret_cast<const float4*>(gamma + 1 * F_LEN)[lane];
    const float4 g2 = reinterpret_cast<const float4*>(gamma + 2 * F_LEN)[lane];
    const float4 b0 = reinterpret_cast<const float4*>(beta  + 0 * F_LEN)[lane];
    const float4 b1 = reinterpret_cast<const float4*>(beta  + 1 * F_LEN)[lane];
    const float4 b2 = reinterpret_cast<const float4*>(beta  + 2 * F_LEN)[lane];

    float4 ov;
    {
        float G  = m0*g0.x + m1*g1.x + m2*g2.x;
        float Bv = m0*b0.x + m1*b1.x + m2*b2.x;
        ov.x = (xv.x - mean) * rstd * G + Bv;
        G  = m0*g0.y + m1*g1.y + m2*g2.y;
        Bv = m0*b0.y + m1*b1.y + m2*b2.y;
        ov.y = (xv.y - mean) * rstd * G + Bv;
        G  = m0*g0.z + m1*g1.z + m2*g2.z;
        Bv = m0*b0.z + m1*b1.z + m2*b2.z;
        ov.z = (xv.z - mean) * rstd * G + Bv;
        G  = m0*g0.w + m1*g1.w + m2*g2.w;
        Bv = m0*b0.w + m1*b1.w + m2*b2.w;
        ov.w = (xv.w - mean) * rstd * G + Bv;
    }

    reinterpret_cast<float4*>(out + base)[lane] = ov;
}

extern "C" void kernel_launch(void* const* d_in, const int* in_sizes, int n_in,
                              void* d_out, int out_size, void* d_ws, size_t ws_size,
                              hipStream_t stream) {
    const float* x       = (const float*)d_in[0];
    const float* gamma   = (const float*)d_in[1];
    const float* beta    = (const float*)d_in[2];
    const float* weights = (const float*)d_in[3];
    float* out = (float*)d_out;

    const int n_rows = out_size / F_LEN;          // B*S = 131072
    const int blocks = (n_rows + 3) / 4;          // 4 rows per 256-thread block

    fan_ln_kernel<<<blocks, 256, 0, stream>>>(x, gamma, beta, weights, out, n_rows);
}